// Round 7
// baseline (264.767 us; speedup 1.0000x reference)
//
#include <hip/hip_runtime.h>
#include <hip/hip_bf16.h>

typedef __bf16 bf16x8 __attribute__((ext_vector_type(8)));
typedef float  f32x4  __attribute__((ext_vector_type(4)));

#define NB   64      // batch
#define NPTS 10000   // nodes
#define KC0  128     // feature channels (GEMM K)
#define NC1  64      // kernel MLP out channels
#define NC2  256     // encoder out channels (GEMM M after operand swap)
#define GN   4       // n-tiles per block -> 2500 blocks

// ---------------------------------------------------------------------------
// Kernel 1: precompute, 9 blocks.
//   block 0 : k0 = MLP(0); cst = k0 @ We[128:192,:] + be   [256] exact fp32
//   block b : WeT[c][k] = bf16(We[k][c]) for k-slice [(b-1)*16, (b-1)*16+16),
//             staged via LDS so global writes are 16B segments.
// ---------------------------------------------------------------------------
__global__ __launch_bounds__(256) void pe_precompute(
    const float* __restrict__ b1, const float* __restrict__ W2,
    const float* __restrict__ b2, const float* __restrict__ W3,
    const float* __restrict__ b3, const float* __restrict__ We,
    const float* __restrict__ be,
    __hip_bfloat16* __restrict__ WeT, float* __restrict__ cst)
{
    const int t  = threadIdx.x;
    const int bb = blockIdx.x;
    if (bb == 0) {
        __shared__ float sW2[8 * 16], sW3[16 * NC1], sb1[8], sb2[16], sb3[NC1], k0[NC1];
        if (t < 128) sW2[t] = W2[t];
        for (int i = t; i < 16 * NC1; i += 256) sW3[i] = W3[i];
        if (t < 8)  sb1[t] = b1[t];
        if (t < 16) sb2[t] = b2[t];
        if (t < NC1) sb3[t] = b3[t];
        __syncthreads();
        if (t < NC1) {
            float h1[8], h2[16];
            #pragma unroll
            for (int i = 0; i < 8; ++i) h1[i] = fmaxf(sb1[i], 0.f);  // x=0 -> relu(b1)
            #pragma unroll
            for (int j = 0; j < 16; ++j) {
                float s = sb2[j];
                #pragma unroll
                for (int i = 0; i < 8; ++i) s += h1[i] * sW2[i * 16 + j];
                h2[j] = fmaxf(s, 0.f);
            }
            float s = sb3[t];
            #pragma unroll
            for (int j = 0; j < 16; ++j) s += h2[j] * sW3[j * NC1 + t];
            k0[t] = s;
        }
        __syncthreads();
        float s = be[t];
        #pragma unroll 8
        for (int j = 0; j < NC1; ++j)
            s += k0[j] * We[(size_t)(KC0 + j) * NC2 + t];
        cst[t] = s;
    } else {
        __shared__ float sW[16][NC2];
        const int kbase = (bb - 1) * 16;
        #pragma unroll
        for (int kk = 0; kk < 16; ++kk)
            sW[kk][t] = We[(size_t)(kbase + kk) * NC2 + t];  // coalesced reads
        __syncthreads();
        bf16x8 lo, hi;
        #pragma unroll
        for (int kk = 0; kk < 8; ++kk) {
            lo[kk] = (__bf16)sW[kk][t];
            hi[kk] = (__bf16)sW[kk + 8][t];
        }
        __hip_bfloat16* wp = WeT + (size_t)t * KC0 + kbase;
        *reinterpret_cast<bf16x8*>(wp)     = lo;
        *reinterpret_cast<bf16x8*>(wp + 8) = hi;
    }
}

// ---------------------------------------------------------------------------
// Kernel 2: out[n,b,c] = feature[b,n,:] @ We[:128,c] + cst[c]
// 512 thr / 8 waves; wave w owns c in [w*32,w*32+32).
// Depth-3 pipeline: 3 named register sets LA/LB/LC (rule #20: static only).
// Every ds_write consumes loads >= 2 compute-tiles in flight; the barrier
// carries no vmcnt drain (raw s_barrier).
// LDS: bf16 [64 b][128 k], 16B-granule involution gs = g ^ (row&7) applied
// at write AND read (rule #21) -> conflict-free b128 both sides.
// MFMA 16x16x32 (m89-verified), A = WeT (c x k), B = feature (k x b):
//   A: lane l -> A[l&15][8*(l>>4)+j]        B: lane l -> B[8*(l>>4)+j][l&15]
//   D: lane l, reg r -> D[(l>>4)*4+r][l&15] (c = lk*4+r consecutive -> f32x4 st)
// THIS ROUND'S single variable: output stores are NON-TEMPORAL (nt flag) --
// output is write-once/never-read; goal is to stop the 655 MB write stream
// from evicting the feature from L2/L3 so replay reads hit Infinity Cache.
// ---------------------------------------------------------------------------
#define SYNC() do { \
    __builtin_amdgcn_sched_barrier(0); \
    asm volatile("s_waitcnt lgkmcnt(0)" ::: "memory"); \
    __builtin_amdgcn_s_barrier(); \
    __builtin_amdgcn_sched_barrier(0); \
} while (0)

__global__ __launch_bounds__(512, 4) void pe_gemm(
    const float* __restrict__ feat, const __hip_bfloat16* __restrict__ WeT,
    const float* __restrict__ cst, float* __restrict__ out)
{
    __shared__ __align__(16) __bf16 sbuf[2][64 * KC0];   // 2 x 16 KB

    const int tid  = threadIdx.x;
    const int wave = tid >> 6;       // 0..7
    const int lane = tid & 63;
    const int lm   = lane & 15;
    const int lk   = lane >> 4;
    const int cbase = wave * 32;

    // staging role: row sr (b), octant sq; k-segments [sq*8,+8) and [64+sq*8,+8)
    const int sr = tid >> 3;         // 0..63
    const int sq = tid & 7;          // 0..7
    const size_t n0 = (size_t)blockIdx.x * GN;
    const float* fstage = feat + ((size_t)sr * NPTS + n0) * KC0 + sq * 8;
    const int gsA = sq ^ (sr & 7);   // swizzled granule (segment A); B = +8
    __bf16* const wp0 = &sbuf[0][sr * KC0 + gsA * 8];   // segment A, buf 0
    const int BUFSTEP = 64 * KC0;                       // buf1 = wp0 + BUFSTEP

    // A fragments (WeT) + bias, resident for the whole block
    bf16x8 afrag[4][2];
    #pragma unroll
    for (int nn = 0; nn < 2; ++nn) {
        const __hip_bfloat16* wp = WeT + (size_t)(cbase + nn * 16 + lm) * KC0 + lk * 8;
        #pragma unroll
        for (int kk = 0; kk < 4; ++kk)
            afrag[kk][nn] = *reinterpret_cast<const bf16x8*>(wp + kk * 32);
    }
    f32x4 cv0 = *reinterpret_cast<const f32x4*>(cst + cbase + lk * 4);
    f32x4 cv1 = *reinterpret_cast<const f32x4*>(cst + cbase + 16 + lk * 4);

#define LOAD_TILE(L, t) do { \
    const float* fs_ = fstage + (t) * KC0; \
    L[0] = *reinterpret_cast<const f32x4*>(fs_); \
    L[1] = *reinterpret_cast<const f32x4*>(fs_ + 4); \
    L[2] = *reinterpret_cast<const f32x4*>(fs_ + 64); \
    L[3] = *reinterpret_cast<const f32x4*>(fs_ + 68); \
} while (0)

#define WRITE_TILE(L, buf) do { \
    bf16x8 hA_, hB_; \
    _Pragma("unroll") \
    for (int j = 0; j < 4; ++j) { \
        hA_[j] = (__bf16)L[0][j];  hA_[j + 4] = (__bf16)L[1][j]; \
        hB_[j] = (__bf16)L[2][j];  hB_[j + 4] = (__bf16)L[3][j]; \
    } \
    *reinterpret_cast<bf16x8*>(wp0 + (buf) * BUFSTEP)      = hA_; \
    *reinterpret_cast<bf16x8*>(wp0 + (buf) * BUFSTEP + 64) = hB_; \
} while (0)

#define COMPUTE_TILE(t, buf) do { \
    const __bf16* sb_ = &sbuf[buf][0]; \
    float* on_ = out + ((n0 + (t)) * NB) * NC2 + cbase + lk * 4; \
    _Pragma("unroll") \
    for (int mm = 0; mm < 4; ++mm) { \
        const int row_ = mm * 16 + lm; \
        bf16x8 bfr_[4]; \
        _Pragma("unroll") \
        for (int kk = 0; kk < 4; ++kk) { \
            const int gs_ = (kk * 4 + lk) ^ (lm & 7); \
            bfr_[kk] = *reinterpret_cast<const bf16x8*>(sb_ + row_ * KC0 + gs_ * 8); \
        } \
        f32x4 a0_ = cv0, a1_ = cv1; \
        _Pragma("unroll") \
        for (int kk = 0; kk < 4; ++kk) { \
            a0_ = __builtin_amdgcn_mfma_f32_16x16x32_bf16(afrag[kk][0], bfr_[kk], a0_, 0, 0, 0); \
            a1_ = __builtin_amdgcn_mfma_f32_16x16x32_bf16(afrag[kk][1], bfr_[kk], a1_, 0, 0, 0); \
        } \
        float* op_ = on_ + (size_t)row_ * NC2; \
        __builtin_nontemporal_store(a0_, reinterpret_cast<f32x4*>(op_)); \
        __builtin_nontemporal_store(a1_, reinterpret_cast<f32x4*>(op_ + 16)); \
    } \
} while (0)

    f32x4 LA[4], LB[4], LC[4];
    // prologue: 12 loads in flight, then stage tile 0
    LOAD_TILE(LA, 0);
    LOAD_TILE(LB, 1);
    LOAD_TILE(LC, 2);
    WRITE_TILE(LA, 0);          // waits only LA's 4 loads

    LOAD_TILE(LA, 3);           // reuse set A for tile 3
    SYNC();
    COMPUTE_TILE(0, 0);
    WRITE_TILE(LB, 1);          // tile 1 -> buf1 (LB ~2 tiles in flight)

    SYNC();
    COMPUTE_TILE(1, 1);
    WRITE_TILE(LC, 0);          // tile 2 -> buf0 (readers of buf0 passed barrier)

    SYNC();
    COMPUTE_TILE(2, 0);
    WRITE_TILE(LA, 1);          // tile 3 -> buf1

    SYNC();
    COMPUTE_TILE(3, 1);

#undef LOAD_TILE
#undef WRITE_TILE
#undef COMPUTE_TILE
}

extern "C" void kernel_launch(void* const* d_in, const int* in_sizes, int n_in,
                              void* d_out, int out_size, void* d_ws, size_t ws_size,
                              hipStream_t stream) {
    const float* feat = (const float*)d_in[0];
    // d_in[1] = coordinates: unused (MLP input is identically zero)
    // d_in[2] = W1: unused (multiplies the zero vector)
    const float* b1 = (const float*)d_in[3];
    const float* W2 = (const float*)d_in[4];
    const float* b2 = (const float*)d_in[5];
    const float* W3 = (const float*)d_in[6];
    const float* b3 = (const float*)d_in[7];
    const float* We = (const float*)d_in[8];
    const float* be = (const float*)d_in[9];

    __hip_bfloat16* WeT = (__hip_bfloat16*)d_ws;                    // 256*128*2 = 64 KiB
    float*          cst = (float*)((char*)d_ws + NC2 * KC0 * 2);    // 256 floats, 16B-aligned

    pe_precompute<<<9, 256, 0, stream>>>(b1, W2, b2, W3, b3, We, be, WeT, cst);
    pe_gemm<<<NPTS / GN, 512, 0, stream>>>(feat, WeT, cst, (float*)d_out);
}

// Round 8
// 217.263 us; speedup vs baseline: 1.2187x; 1.2187x over previous
//
#include <hip/hip_runtime.h>
#include <hip/hip_bf16.h>

typedef __bf16 bf16x8 __attribute__((ext_vector_type(8)));
typedef float  f32x4  __attribute__((ext_vector_type(4)));

#define NB   64      // batch
#define NPTS 10000   // nodes
#define KC0  128     // feature channels (GEMM K)
#define NC1  64      // kernel MLP out channels
#define NC2  256     // encoder out channels (GEMM M after operand swap)
#define TPB  20      // n-tiles per block -> 500 persistent-ish blocks (2/CU)

// ---------------------------------------------------------------------------
// Kernel 1: precompute, 9 blocks.
//   block 0 : k0 = MLP(0); cst = k0 @ We[128:192,:] + be   [256] exact fp32
//   block b : WeT[c][k] = bf16(We[k][c]) for k-slice [(b-1)*16, (b-1)*16+16),
//             staged via LDS so global writes are 16B segments.
// ---------------------------------------------------------------------------
__global__ __launch_bounds__(256) void pe_precompute(
    const float* __restrict__ b1, const float* __restrict__ W2,
    const float* __restrict__ b2, const float* __restrict__ W3,
    const float* __restrict__ b3, const float* __restrict__ We,
    const float* __restrict__ be,
    __hip_bfloat16* __restrict__ WeT, float* __restrict__ cst)
{
    const int t  = threadIdx.x;
    const int bb = blockIdx.x;
    if (bb == 0) {
        __shared__ float sW2[8 * 16], sW3[16 * NC1], sb1[8], sb2[16], sb3[NC1], k0[NC1];
        if (t < 128) sW2[t] = W2[t];
        for (int i = t; i < 16 * NC1; i += 256) sW3[i] = W3[i];
        if (t < 8)  sb1[t] = b1[t];
        if (t < 16) sb2[t] = b2[t];
        if (t < NC1) sb3[t] = b3[t];
        __syncthreads();
        if (t < NC1) {
            float h1[8], h2[16];
            #pragma unroll
            for (int i = 0; i < 8; ++i) h1[i] = fmaxf(sb1[i], 0.f);  // x=0 -> relu(b1)
            #pragma unroll
            for (int j = 0; j < 16; ++j) {
                float s = sb2[j];
                #pragma unroll
                for (int i = 0; i < 8; ++i) s += h1[i] * sW2[i * 16 + j];
                h2[j] = fmaxf(s, 0.f);
            }
            float s = sb3[t];
            #pragma unroll
            for (int j = 0; j < 16; ++j) s += h2[j] * sW3[j * NC1 + t];
            k0[t] = s;
        }
        __syncthreads();
        float s = be[t];
        #pragma unroll 8
        for (int j = 0; j < NC1; ++j)
            s += k0[j] * We[(size_t)(KC0 + j) * NC2 + t];
        cst[t] = s;
    } else {
        __shared__ float sW[16][NC2];
        const int kbase = (bb - 1) * 16;
        #pragma unroll
        for (int kk = 0; kk < 16; ++kk)
            sW[kk][t] = We[(size_t)(kbase + kk) * NC2 + t];  // coalesced reads
        __syncthreads();
        bf16x8 lo, hi;
        #pragma unroll
        for (int kk = 0; kk < 8; ++kk) {
            lo[kk] = (__bf16)sW[kk][t];
            hi[kk] = (__bf16)sW[kk + 8][t];
        }
        __hip_bfloat16* wp = WeT + (size_t)t * KC0 + kbase;
        *reinterpret_cast<bf16x8*>(wp)     = lo;
        *reinterpret_cast<bf16x8*>(wp + 8) = hi;
    }
}

// ---------------------------------------------------------------------------
// Kernel 2: out[n,b,c] = feature[b,n,:] @ We[:128,c] + cst[c]
// 500 blocks x 512 thr (8 waves); block owns 20 CONSECUTIVE n.
//   -> each of the block's 64 feature row-streams is 10 KB sequential
//      (vs 2 KB before): DRAM page locality; output 1.25 MB contiguous.
//   -> prologue (afrag + pipeline fill) amortized over 20 tiles; no tail.
// Depth-2 rotation, two named register sets LA/LB (rule #20: static idx);
// raw s_barrier + lgkmcnt(0) only (no vmcnt drain) — proven structure of
// rounds 4-6. LDS: bf16 [64 b][128 k] x2, 16B-granule involution
// gs = g ^ (row&7) at write AND read (rule #21) -> conflict-free b128.
// MFMA 16x16x32 (m89-verified), A = WeT (c x k), B = feature (k x b):
//   A: lane l -> A[l&15][8*(l>>4)+j]        B: lane l -> B[8*(l>>4)+j][l&15]
//   D: lane l, reg r -> D[(l>>4)*4+r][l&15] (c = lk*4+r consecutive -> f32x4)
// Stores: PLAIN cached f32x4 (NT regressed 214->265 in round 7; reverted).
// ---------------------------------------------------------------------------
#define SYNC() do { \
    __builtin_amdgcn_sched_barrier(0); \
    asm volatile("s_waitcnt lgkmcnt(0)" ::: "memory"); \
    __builtin_amdgcn_s_barrier(); \
    __builtin_amdgcn_sched_barrier(0); \
} while (0)

__global__ __launch_bounds__(512, 4) void pe_gemm(
    const float* __restrict__ feat, const __hip_bfloat16* __restrict__ WeT,
    const float* __restrict__ cst, float* __restrict__ out)
{
    __shared__ __align__(16) __bf16 sbuf[2][64 * KC0];   // 2 x 16 KB

    const int tid  = threadIdx.x;
    const int wave = tid >> 6;       // 0..7
    const int lane = tid & 63;
    const int lm   = lane & 15;
    const int lk   = lane >> 4;
    const int cbase = wave * 32;

    // staging role: row sr (b), octant sq; k-segments [sq*8,+8) and [64+sq*8,+8)
    const int sr = tid >> 3;         // 0..63
    const int sq = tid & 7;          // 0..7
    const size_t n0 = (size_t)blockIdx.x * TPB;
    const float* fstage = feat + ((size_t)sr * NPTS + n0) * KC0 + sq * 8;
    const int gsA = sq ^ (sr & 7);   // swizzled granule (segment A); B = +8
    __bf16* const wp0 = &sbuf[0][sr * KC0 + gsA * 8];   // segment A, buf 0
    const int BUFSTEP = 64 * KC0;                       // buf1 = wp0 + BUFSTEP

    // A fragments (WeT) + bias, resident for the whole block
    bf16x8 afrag[4][2];
    #pragma unroll
    for (int nn = 0; nn < 2; ++nn) {
        const __hip_bfloat16* wp = WeT + (size_t)(cbase + nn * 16 + lm) * KC0 + lk * 8;
        #pragma unroll
        for (int kk = 0; kk < 4; ++kk)
            afrag[kk][nn] = *reinterpret_cast<const bf16x8*>(wp + kk * 32);
    }
    f32x4 cv0 = *reinterpret_cast<const f32x4*>(cst + cbase + lk * 4);
    f32x4 cv1 = *reinterpret_cast<const f32x4*>(cst + cbase + 16 + lk * 4);

#define LOAD_TILE(L, t) do { \
    const float* fs_ = fstage + (size_t)(t) * KC0; \
    L[0] = *reinterpret_cast<const f32x4*>(fs_); \
    L[1] = *reinterpret_cast<const f32x4*>(fs_ + 4); \
    L[2] = *reinterpret_cast<const f32x4*>(fs_ + 64); \
    L[3] = *reinterpret_cast<const f32x4*>(fs_ + 68); \
} while (0)

#define WRITE_TILE(L, buf) do { \
    bf16x8 hA_, hB_; \
    _Pragma("unroll") \
    for (int j = 0; j < 4; ++j) { \
        hA_[j] = (__bf16)L[0][j];  hA_[j + 4] = (__bf16)L[1][j]; \
        hB_[j] = (__bf16)L[2][j];  hB_[j + 4] = (__bf16)L[3][j]; \
    } \
    *reinterpret_cast<bf16x8*>(wp0 + (buf) * BUFSTEP)      = hA_; \
    *reinterpret_cast<bf16x8*>(wp0 + (buf) * BUFSTEP + 64) = hB_; \
} while (0)

#define COMPUTE_TILE(t, buf) do { \
    const __bf16* sb_ = &sbuf[buf][0]; \
    float* on_ = out + ((n0 + (t)) * NB) * NC2 + cbase + lk * 4; \
    _Pragma("unroll") \
    for (int mm = 0; mm < 4; ++mm) { \
        const int row_ = mm * 16 + lm; \
        bf16x8 bfr_[4]; \
        _Pragma("unroll") \
        for (int kk = 0; kk < 4; ++kk) { \
            const int gs_ = (kk * 4 + lk) ^ (lm & 7); \
            bfr_[kk] = *reinterpret_cast<const bf16x8*>(sb_ + row_ * KC0 + gs_ * 8); \
        } \
        f32x4 a0_ = cv0, a1_ = cv1; \
        _Pragma("unroll") \
        for (int kk = 0; kk < 4; ++kk) { \
            a0_ = __builtin_amdgcn_mfma_f32_16x16x32_bf16(afrag[kk][0], bfr_[kk], a0_, 0, 0, 0); \
            a1_ = __builtin_amdgcn_mfma_f32_16x16x32_bf16(afrag[kk][1], bfr_[kk], a1_, 0, 0, 0); \
        } \
        float* op_ = on_ + (size_t)row_ * NC2; \
        *reinterpret_cast<f32x4*>(op_)      = a0_; \
        *reinterpret_cast<f32x4*>(op_ + 16) = a1_; \
    } \
} while (0)

    f32x4 LA[4], LB[4];
    // ---- pipeline fill ----
    LOAD_TILE(LA, 0);
    LOAD_TILE(LB, 1);
    WRITE_TILE(LA, 0);          // tile 0 -> buf0
    LOAD_TILE(LA, 2);

    // ---- steady loop: tiles 0..15 (8 double-iterations) ----
    // invariant at loop top: buf0 = tile i, LB = tile i+1, LA = tile i+2
    for (int i = 0; i < 16; i += 2) {
        SYNC();
        COMPUTE_TILE(i, 0);
        WRITE_TILE(LB, 1);      // tile i+1 -> buf1
        LOAD_TILE(LB, i + 3);   // i+3 <= 17
        SYNC();
        COMPUTE_TILE(i + 1, 1);
        WRITE_TILE(LA, 0);      // tile i+2 -> buf0
        LOAD_TILE(LA, i + 4);   // i+4 <= 18
    }
    // ---- epilogue: buf0 = tile 16, LB = tile 17, LA = tile 18 ----
    SYNC();
    COMPUTE_TILE(16, 0);
    WRITE_TILE(LB, 1);          // tile 17
    LOAD_TILE(LB, 19);
    SYNC();
    COMPUTE_TILE(17, 1);
    WRITE_TILE(LA, 0);          // tile 18
    SYNC();
    COMPUTE_TILE(18, 0);
    WRITE_TILE(LB, 1);          // tile 19
    SYNC();
    COMPUTE_TILE(19, 1);

#undef LOAD_TILE
#undef WRITE_TILE
#undef COMPUTE_TILE
}

extern "C" void kernel_launch(void* const* d_in, const int* in_sizes, int n_in,
                              void* d_out, int out_size, void* d_ws, size_t ws_size,
                              hipStream_t stream) {
    const float* feat = (const float*)d_in[0];
    // d_in[1] = coordinates: unused (MLP input is identically zero)
    // d_in[2] = W1: unused (multiplies the zero vector)
    const float* b1 = (const float*)d_in[3];
    const float* W2 = (const float*)d_in[4];
    const float* b2 = (const float*)d_in[5];
    const float* W3 = (const float*)d_in[6];
    const float* b3 = (const float*)d_in[7];
    const float* We = (const float*)d_in[8];
    const float* be = (const float*)d_in[9];

    __hip_bfloat16* WeT = (__hip_bfloat16*)d_ws;                    // 256*128*2 = 64 KiB
    float*          cst = (float*)((char*)d_ws + NC2 * KC0 * 2);    // 256 floats, 16B-aligned

    pe_precompute<<<9, 256, 0, stream>>>(b1, W2, b2, W3, b3, We, be, WeT, cst);
    pe_gemm<<<NPTS / TPB, 512, 0, stream>>>(feat, WeT, cst, (float*)d_out);
}

// Round 9
// 213.180 us; speedup vs baseline: 1.2420x; 1.0191x over previous
//
#include <hip/hip_runtime.h>
#include <hip/hip_bf16.h>

typedef __bf16 bf16x8 __attribute__((ext_vector_type(8)));
typedef float  f32x4  __attribute__((ext_vector_type(4)));

#define NB   64      // batch
#define NPTS 10000   // nodes
#define KC0  128     // feature channels (GEMM K)
#define NC1  64      // kernel MLP out channels
#define NC2  256     // encoder out channels (GEMM M after operand swap)
#define GN   4       // n-tiles per block -> 2500 blocks (round-6 baseline)

// ---------------------------------------------------------------------------
// Kernel 1: precompute, 9 blocks.  (unchanged since round 5)
//   block 0 : k0 = MLP(0); cst = k0 @ We[128:192,:] + be   [256] exact fp32
//   block b : WeT[c][k] = bf16(We[k][c]) for k-slice [(b-1)*16, (b-1)*16+16)
// ---------------------------------------------------------------------------
__global__ __launch_bounds__(256) void pe_precompute(
    const float* __restrict__ b1, const float* __restrict__ W2,
    const float* __restrict__ b2, const float* __restrict__ W3,
    const float* __restrict__ b3, const float* __restrict__ We,
    const float* __restrict__ be,
    __hip_bfloat16* __restrict__ WeT, float* __restrict__ cst)
{
    const int t  = threadIdx.x;
    const int bb = blockIdx.x;
    if (bb == 0) {
        __shared__ float sW2[8 * 16], sW3[16 * NC1], sb1[8], sb2[16], sb3[NC1], k0[NC1];
        if (t < 128) sW2[t] = W2[t];
        for (int i = t; i < 16 * NC1; i += 256) sW3[i] = W3[i];
        if (t < 8)  sb1[t] = b1[t];
        if (t < 16) sb2[t] = b2[t];
        if (t < NC1) sb3[t] = b3[t];
        __syncthreads();
        if (t < NC1) {
            float h1[8], h2[16];
            #pragma unroll
            for (int i = 0; i < 8; ++i) h1[i] = fmaxf(sb1[i], 0.f);  // x=0 -> relu(b1)
            #pragma unroll
            for (int j = 0; j < 16; ++j) {
                float s = sb2[j];
                #pragma unroll
                for (int i = 0; i < 8; ++i) s += h1[i] * sW2[i * 16 + j];
                h2[j] = fmaxf(s, 0.f);
            }
            float s = sb3[t];
            #pragma unroll
            for (int j = 0; j < 16; ++j) s += h2[j] * sW3[j * NC1 + t];
            k0[t] = s;
        }
        __syncthreads();
        float s = be[t];
        #pragma unroll 8
        for (int j = 0; j < NC1; ++j)
            s += k0[j] * We[(size_t)(KC0 + j) * NC2 + t];
        cst[t] = s;
    } else {
        __shared__ float sW[16][NC2];
        const int kbase = (bb - 1) * 16;
        #pragma unroll
        for (int kk = 0; kk < 16; ++kk)
            sW[kk][t] = We[(size_t)(kbase + kk) * NC2 + t];  // coalesced reads
        __syncthreads();
        bf16x8 lo, hi;
        #pragma unroll
        for (int kk = 0; kk < 8; ++kk) {
            lo[kk] = (__bf16)sW[kk][t];
            hi[kk] = (__bf16)sW[kk + 8][t];
        }
        __hip_bfloat16* wp = WeT + (size_t)t * KC0 + kbase;
        *reinterpret_cast<bf16x8*>(wp)     = lo;
        *reinterpret_cast<bf16x8*>(wp + 8) = hi;
    }
}

// ---------------------------------------------------------------------------
// Kernel 2: out[n,b,c] = feature[b,n,:] @ We[:128,c] + cst[c]
// EXACT round-6 structure (best measured, 213.8 us): 512 thr / 8 waves,
// GN=4, depth-3 register prefetch LA/LB/LC, raw s_barrier + lgkmcnt(0) only,
// input LDS involution swizzle gs = g ^ (row&7) both sides.
// SINGLE CHANGE (this round's variable): full-line store epilogue.
//   Old: per instruction a wave wrote 16 scattered 64-B segments (other half
//        of each 128-B line came from a different instruction) -> round-3
//        profile showed WRITE_SIZE 1.23x ideal (partial-line flush).
//   New: wave stages acc into a WAVE-PRIVATE granule-major LDS buffer
//        [g:8][row:32] (16-B granules), in-wave lgkmcnt only (no barrier),
//        then each global_store_dwordx4 writes 8 rows x 128-B contiguous,
//        128-B-aligned chunks = 8 FULL lines per instruction.
//   Bank evenness (16-B granule index & 7): write = lm&7 (8 lanes/set),
//   read = (lane>>3)&7 (8 lanes/set) -> both perfect sweeps, 0 conflicts.
// MFMA 16x16x32 (m89-verified), A = WeT (c x k), B = feature (k x b):
//   A: lane l -> A[l&15][8*(l>>4)+j]        B: lane l -> B[8*(l>>4)+j][l&15]
//   D: lane l, reg r -> D[(l>>4)*4+r][l&15] (c = lk*4+r consecutive)
// ---------------------------------------------------------------------------
#define SYNC() do { \
    __builtin_amdgcn_sched_barrier(0); \
    asm volatile("s_waitcnt lgkmcnt(0)" ::: "memory"); \
    __builtin_amdgcn_s_barrier(); \
    __builtin_amdgcn_sched_barrier(0); \
} while (0)

__global__ __launch_bounds__(512, 4) void pe_gemm(
    const float* __restrict__ feat, const __hip_bfloat16* __restrict__ WeT,
    const float* __restrict__ cst, float* __restrict__ out)
{
    __shared__ __align__(16) __bf16 sbuf[2][64 * KC0];   // input dbuf: 2 x 16 KB
    __shared__ __align__(16) f32x4  sOut[8][8 * 32];     // out stage: 8 waves x 4 KB

    const int tid  = threadIdx.x;
    const int wave = tid >> 6;       // 0..7
    const int lane = tid & 63;
    const int lm   = lane & 15;
    const int lk   = lane >> 4;
    const int cbase = wave * 32;
    f32x4* const sOutW = sOut[wave]; // wave-private: no cross-wave sync needed

    // staging role: row sr (b), octant sq; k-segments [sq*8,+8) and [64+sq*8,+8)
    const int sr = tid >> 3;         // 0..63
    const int sq = tid & 7;          // 0..7
    const size_t n0 = (size_t)blockIdx.x * GN;
    const float* fstage = feat + ((size_t)sr * NPTS + n0) * KC0 + sq * 8;
    const int gsA = sq ^ (sr & 7);   // swizzled granule (segment A); B = +8
    __bf16* const wp0 = &sbuf[0][sr * KC0 + gsA * 8];   // segment A, buf 0
    const int BUFSTEP = 64 * KC0;                       // buf1 = wp0 + BUFSTEP

    // A fragments (WeT) + bias, resident for the whole block
    bf16x8 afrag[4][2];
    #pragma unroll
    for (int nn = 0; nn < 2; ++nn) {
        const __hip_bfloat16* wp = WeT + (size_t)(cbase + nn * 16 + lm) * KC0 + lk * 8;
        #pragma unroll
        for (int kk = 0; kk < 4; ++kk)
            afrag[kk][nn] = *reinterpret_cast<const bf16x8*>(wp + kk * 32);
    }
    f32x4 cv0 = *reinterpret_cast<const f32x4*>(cst + cbase + lk * 4);
    f32x4 cv1 = *reinterpret_cast<const f32x4*>(cst + cbase + 16 + lk * 4);

#define LOAD_TILE(L, t) do { \
    const float* fs_ = fstage + (size_t)(t) * KC0; \
    L[0] = *reinterpret_cast<const f32x4*>(fs_); \
    L[1] = *reinterpret_cast<const f32x4*>(fs_ + 4); \
    L[2] = *reinterpret_cast<const f32x4*>(fs_ + 64); \
    L[3] = *reinterpret_cast<const f32x4*>(fs_ + 68); \
} while (0)

#define WRITE_TILE(L, buf) do { \
    bf16x8 hA_, hB_; \
    _Pragma("unroll") \
    for (int j = 0; j < 4; ++j) { \
        hA_[j] = (__bf16)L[0][j];  hA_[j + 4] = (__bf16)L[1][j]; \
        hB_[j] = (__bf16)L[2][j];  hB_[j + 4] = (__bf16)L[3][j]; \
    } \
    *reinterpret_cast<bf16x8*>(wp0 + (buf) * BUFSTEP)      = hA_; \
    *reinterpret_cast<bf16x8*>(wp0 + (buf) * BUFSTEP + 64) = hB_; \
} while (0)

// Compute one n-tile from sbuf[buf]; epilogue stages each 32-row half in
// wave-private LDS, then streams 4 x (8 rows x 128 B full lines).
#define COMPUTE_TILE(t, buf) do { \
    const __bf16* sb_ = &sbuf[buf][0]; \
    float* on_ = out + ((n0 + (t)) * NB) * NC2 + cbase; \
    _Pragma("unroll") \
    for (int h_ = 0; h_ < 2; ++h_) { \
        _Pragma("unroll") \
        for (int m_ = 0; m_ < 2; ++m_) { \
            const int row_ = h_ * 32 + m_ * 16 + lm; \
            bf16x8 bfr_[4]; \
            _Pragma("unroll") \
            for (int kk = 0; kk < 4; ++kk) { \
                const int gs_ = (kk * 4 + lk) ^ (lm & 7); \
                bfr_[kk] = *reinterpret_cast<const bf16x8*>(sb_ + row_ * KC0 + gs_ * 8); \
            } \
            f32x4 a0_ = cv0, a1_ = cv1; \
            _Pragma("unroll") \
            for (int kk = 0; kk < 4; ++kk) { \
                a0_ = __builtin_amdgcn_mfma_f32_16x16x32_bf16(afrag[kk][0], bfr_[kk], a0_, 0, 0, 0); \
                a1_ = __builtin_amdgcn_mfma_f32_16x16x32_bf16(afrag[kk][1], bfr_[kk], a1_, 0, 0, 0); \
            } \
            /* stage: granule-major [g][row32], g=lk / lk+4, row=m_*16+lm */ \
            sOutW[lk * 32 + m_ * 16 + lm]       = a0_; \
            sOutW[(lk + 4) * 32 + m_ * 16 + lm] = a1_; \
        } \
        asm volatile("s_waitcnt lgkmcnt(0)" ::: "memory"); /* in-wave only */ \
        _Pragma("unroll") \
        for (int p_ = 0; p_ < 4; ++p_) { \
            const int rr_ = p_ * 8 + (lane >> 3); \
            f32x4 v_ = sOutW[(lane & 7) * 32 + rr_]; \
            *reinterpret_cast<f32x4*>( \
                on_ + (size_t)(h_ * 32 + rr_) * NC2 + (lane & 7) * 4) = v_; \
        } \
    } \
} while (0)

    f32x4 LA[4], LB[4], LC[4];
    // prologue: 12 loads in flight, then stage tile 0
    LOAD_TILE(LA, 0);
    LOAD_TILE(LB, 1);
    LOAD_TILE(LC, 2);
    WRITE_TILE(LA, 0);          // waits only LA's 4 loads

    LOAD_TILE(LA, 3);           // reuse set A for tile 3
    SYNC();
    COMPUTE_TILE(0, 0);
    WRITE_TILE(LB, 1);          // tile 1 -> buf1 (LB ~2 tiles in flight)

    SYNC();
    COMPUTE_TILE(1, 1);
    WRITE_TILE(LC, 0);          // tile 2 -> buf0 (readers of buf0 passed barrier)

    SYNC();
    COMPUTE_TILE(2, 0);
    WRITE_TILE(LA, 1);          // tile 3 -> buf1

    SYNC();
    COMPUTE_TILE(3, 1);

#undef LOAD_TILE
#undef WRITE_TILE
#undef COMPUTE_TILE
}

extern "C" void kernel_launch(void* const* d_in, const int* in_sizes, int n_in,
                              void* d_out, int out_size, void* d_ws, size_t ws_size,
                              hipStream_t stream) {
    const float* feat = (const float*)d_in[0];
    // d_in[1] = coordinates: unused (MLP input is identically zero)
    // d_in[2] = W1: unused (multiplies the zero vector)
    const float* b1 = (const float*)d_in[3];
    const float* W2 = (const float*)d_in[4];
    const float* b2 = (const float*)d_in[5];
    const float* W3 = (const float*)d_in[6];
    const float* b3 = (const float*)d_in[7];
    const float* We = (const float*)d_in[8];
    const float* be = (const float*)d_in[9];

    __hip_bfloat16* WeT = (__hip_bfloat16*)d_ws;                    // 256*128*2 = 64 KiB
    float*          cst = (float*)((char*)d_ws + NC2 * KC0 * 2);    // 256 floats, 16B-aligned

    pe_precompute<<<9, 256, 0, stream>>>(b1, W2, b2, W3, b3, We, be, WeT, cst);
    pe_gemm<<<NPTS / GN, 512, 0, stream>>>(feat, WeT, cst, (float*)d_out);
}